// Round 5
// baseline (570.333 us; speedup 1.0000x reference)
//
#include <hip/hip_runtime.h>

typedef unsigned short u16;
typedef short short8 __attribute__((ext_vector_type(8)));
typedef unsigned short ushort8 __attribute__((ext_vector_type(8)));
typedef unsigned short bf16x4 __attribute__((ext_vector_type(4)));
typedef float f32x4 __attribute__((ext_vector_type(4)));

#define DEVINL __device__ __forceinline__

DEVINL float bf2f(u16 u) {
  unsigned int x = ((unsigned int)u) << 16;
  return __builtin_bit_cast(float, x);
}
DEVINL u16 f2bf(float f) {
  unsigned int x = __builtin_bit_cast(unsigned int, f);
  x += 0x7FFFu + ((x >> 16) & 1u);  // RNE
  return (u16)(x >> 16);
}

// Problem constants: B=2, S=2048, E=1024, H=16, DH=64
// Inputs float32; big operands converted once to bf16; MFMA internally;
// final output written as float32.

// ---------------------------------------------------------------------------
// Fused f32 -> bf16 conversion of query + 4 weight matrices.
// Destinations are contiguous in ws: [Qb | Wqb | Wkb | Wvb | Wob].
// 8-elem units: query 524288, each W 131072; total 1048576 units.
// ---------------------------------------------------------------------------
__global__ __launch_bounds__(256) void cvt_all(
    const float* __restrict__ q, const float* __restrict__ wq,
    const float* __restrict__ wk, const float* __restrict__ wv,
    const float* __restrict__ wo, u16* __restrict__ out) {
  int i = blockIdx.x * 256 + threadIdx.x;  // < 1048576
  const float* src;
  size_t off8;
  if (i < 524288) { src = q;  off8 = i; }
  else if (i < 655360) { src = wq; off8 = i - 524288; }
  else if (i < 786432) { src = wk; off8 = i - 655360; }
  else if (i < 917504) { src = wv; off8 = i - 786432; }
  else { src = wo; off8 = i - 917504; }
  f32x4 a = ((const f32x4*)src)[2 * off8];
  f32x4 b = ((const f32x4*)src)[2 * off8 + 1];
  ushort8 o;
#pragma unroll
  for (int e = 0; e < 4; ++e) o[e] = f2bf(a[e]);
#pragma unroll
  for (int e = 0; e < 4; ++e) o[4 + e] = f2bf(b[e]);
  ((ushort8*)out)[i] = o;
}

// ---------------------------------------------------------------------------
// NT GEMM (bf16 in via MFMA): C[i,j] = scale * sum_k A[i,k]*B[j,k] (+ bias[j])
// Batched over grid.z; per-z offsets via sAh/sBh/sCh (element strides).
// TRANSV: store C transposed per-batch as Ct[b][j][s] (bf16).
// OUTF32: C is float* (row-major).
// ---------------------------------------------------------------------------
template <int BM, int BN, bool TRANSV, bool HASBIAS, bool OUTF32>
__global__ __launch_bounds__(256) void gemm_nt(
    const u16* __restrict__ A, const u16* __restrict__ Bm,
    const float* __restrict__ bias, void* __restrict__ C,
    int K, int lda, int ldb, int ldc, float scale,
    long long sAh, long long sBh, long long sCh) {
  constexpr int LDSS = 40;  // padded LDS row stride (u16)
  constexpr int WM = BM / 2, WN = BN / 2, FM = WM / 16, FN = WN / 16;
  constexpr int AIN = BM / 64;
  constexpr int BIN = BN / 64;

  __shared__ alignas(16) u16 As[BM * LDSS];
  __shared__ alignas(16) u16 Bs[BN * LDSS];

  const int tid = threadIdx.x;
  const int lane = tid & 63;
  const int wv = tid >> 6;
  const int wy = wv >> 1, wx = wv & 1;
  const int quad = lane >> 4, mrow = lane & 15;

  const int z = blockIdx.z;
  const u16* Ap = A + z * sAh;
  const u16* Bp = Bm + z * sBh;
  u16* Cp = (u16*)C + z * sCh;
  float* Cf = (float*)C + z * sCh;

  const int row0 = blockIdx.y * BM;
  const int col0 = blockIdx.x * BN;

  f32x4 acc[FM][FN];
#pragma unroll
  for (int i = 0; i < FM; ++i)
#pragma unroll
    for (int j = 0; j < FN; ++j) acc[i][j] = f32x4{0.f, 0.f, 0.f, 0.f};

  for (int k0 = 0; k0 < K; k0 += 32) {
    ushort8 ta[AIN], tb[BIN];
#pragma unroll
    for (int r = 0; r < AIN; ++r) {
      int idx = r * 256 + tid;
      int row = idx >> 2, ch = idx & 3;
      ta[r] = *(const ushort8*)(Ap + (size_t)(row0 + row) * lda + k0 + ch * 8);
    }
#pragma unroll
    for (int r = 0; r < BIN; ++r) {
      int idx = r * 256 + tid;
      int row = idx >> 2, ch = idx & 3;
      tb[r] = *(const ushort8*)(Bp + (size_t)(col0 + row) * ldb + k0 + ch * 8);
    }
    __syncthreads();  // previous iteration's LDS reads done
#pragma unroll
    for (int r = 0; r < AIN; ++r) {
      int idx = r * 256 + tid;
      int row = idx >> 2, ch = idx & 3;
      *(ushort8*)&As[row * LDSS + ch * 8] = ta[r];
    }
#pragma unroll
    for (int r = 0; r < BIN; ++r) {
      int idx = r * 256 + tid;
      int row = idx >> 2, ch = idx & 3;
      *(ushort8*)&Bs[row * LDSS + ch * 8] = tb[r];
    }
    __syncthreads();

    short8 af[FM], bfr[FN];
#pragma unroll
    for (int mi = 0; mi < FM; ++mi)
      af[mi] = *(const short8*)&As[(wy * WM + mi * 16 + mrow) * LDSS + quad * 8];
#pragma unroll
    for (int ni = 0; ni < FN; ++ni)
      bfr[ni] = *(const short8*)&Bs[(wx * WN + ni * 16 + mrow) * LDSS + quad * 8];
#pragma unroll
    for (int mi = 0; mi < FM; ++mi)
#pragma unroll
      for (int ni = 0; ni < FN; ++ni)
        acc[mi][ni] = __builtin_amdgcn_mfma_f32_16x16x32_bf16(
            af[mi], bfr[ni], acc[mi][ni], 0, 0, 0);
  }

  // Epilogue. C/D layout: col = lane&15, row = quad*4 + r  [m89/m91 verified]
#pragma unroll
  for (int mi = 0; mi < FM; ++mi) {
    const int rowb = row0 + wy * WM + mi * 16 + quad * 4;
#pragma unroll
    for (int ni = 0; ni < FN; ++ni) {
      const int col = col0 + wx * WN + ni * 16 + mrow;
      float bv = 0.f;
      if (HASBIAS) bv = bias[col];
      f32x4 v = acc[mi][ni];
      if (OUTF32) {
#pragma unroll
        for (int r = 0; r < 4; ++r)
          Cf[(size_t)(rowb + r) * ldc + col] = v[r] * scale + bv;
      } else if (!TRANSV) {
#pragma unroll
        for (int r = 0; r < 4; ++r)
          Cp[(size_t)(rowb + r) * ldc + col] = f2bf(v[r] * scale + bv);
      } else {
        // Ct[b][col][s], per-batch stride E*S = 2097152
        const int bb = rowb >> 11;
        const int ss = rowb & 2047;
        bf16x4 pk;
#pragma unroll
        for (int r = 0; r < 4; ++r) pk[r] = f2bf(v[r] * scale + bv);
        *(bf16x4*)(Cp + (size_t)bb * 2097152 + (size_t)col * 2048 + ss) = pk;
      }
    }
  }
}

// ---------------------------------------------------------------------------
// Cross-head conv1d (KS=3, zero pad) + softmax over key axis, in place on SC.
// SC tile layout [h][q][k], q in [0,qt). One block per q: 512 threads = 8 waves.
// Wave w owns output heads {2w, 2w+1}; lane owns contiguous k in
// [lane*32, lane*32+32) -> per input head: 4 ds_read_b128 + 2 halo u16 reads.
// conv_b skipped: constant along softmax (k) axis -> cancels exactly.
// ---------------------------------------------------------------------------
__global__ __launch_bounds__(512) void conv_softmax(u16* __restrict__ SC,
                                                    const float* __restrict__ cw,
                                                    int qt) {
  __shared__ alignas(16) u16 raw[16][2048];  // 64 KB: all heads' score row
  const int q = blockIdx.x;
  const int tid = threadIdx.x;

  {  // load all 16 head rows, coalesced 16B/lane
    const int h = tid >> 5, l32 = tid & 31;
    const size_t rb = ((size_t)h * qt + q) * 2048;
#pragma unroll
    for (int j = 0; j < 8; ++j) {
      const int off = j * 256 + l32 * 8;
      *(ushort8*)&raw[h][off] = *(const ushort8*)&SC[rb + off];
    }
  }
  __syncthreads();

  const int wv = tid >> 6;
  const int lane = tid & 63;
  const int o0 = wv * 2, o1 = o0 + 1;
  const int k0 = lane * 32;

  float a0[32], a1[32];
#pragma unroll
  for (int e = 0; e < 32; ++e) { a0[e] = 0.f; a1[e] = 0.f; }

#pragma unroll 1
  for (int i = 0; i < 16; ++i) {
    const float w00 = cw[(o0 * 16 + i) * 3 + 0];
    const float w01 = cw[(o0 * 16 + i) * 3 + 1];
    const float w02 = cw[(o0 * 16 + i) * 3 + 2];
    const float w10 = cw[(o1 * 16 + i) * 3 + 0];
    const float w11 = cw[(o1 * 16 + i) * 3 + 1];
    const float w12 = cw[(o1 * 16 + i) * 3 + 2];
    const u16* rw = &raw[i][0];

    ushort8 v[4];
#pragma unroll
    for (int c = 0; c < 4; ++c) v[c] = *(const ushort8*)&rw[k0 + c * 8];
    // halos (clamped address + select so no OOB LDS access)
    float hl = bf2f(rw[(k0 == 0) ? 0 : (k0 - 1)]);
    hl = (lane == 0) ? 0.f : hl;
    float hr = bf2f(rw[(k0 + 32 > 2047) ? 2047 : (k0 + 32)]);
    hr = (lane == 63) ? 0.f : hr;

    float carry = hl;
#pragma unroll
    for (int c = 0; c < 4; ++c) {
      float r[10];
      r[0] = carry;
#pragma unroll
      for (int e = 0; e < 8; ++e) r[e + 1] = bf2f(v[c][e]);
      r[9] = (c < 3) ? bf2f(v[c + 1][0]) : hr;
#pragma unroll
      for (int e = 0; e < 8; ++e) {
        a0[c * 8 + e] = fmaf(w00, r[e], fmaf(w01, r[e + 1], fmaf(w02, r[e + 2], a0[c * 8 + e])));
        a1[c * 8 + e] = fmaf(w10, r[e], fmaf(w11, r[e + 1], fmaf(w12, r[e + 2], a1[c * 8 + e])));
      }
      carry = r[8];
    }
  }

  // softmax over k (2048) per head; each wave holds one full row per head
  float m0 = -3e38f, m1 = -3e38f;
#pragma unroll
  for (int e = 0; e < 32; ++e) {
    m0 = fmaxf(m0, a0[e]);
    m1 = fmaxf(m1, a1[e]);
  }
#pragma unroll
  for (int off = 1; off < 64; off <<= 1) {
    m0 = fmaxf(m0, __shfl_xor(m0, off));
    m1 = fmaxf(m1, __shfl_xor(m1, off));
  }
  float s0 = 0.f, s1 = 0.f;
#pragma unroll
  for (int e = 0; e < 32; ++e) {
    a0[e] = __expf(a0[e] - m0);
    s0 += a0[e];
    a1[e] = __expf(a1[e] - m1);
    s1 += a1[e];
  }
#pragma unroll
  for (int off = 1; off < 64; off <<= 1) {
    s0 += __shfl_xor(s0, off);
    s1 += __shfl_xor(s1, off);
  }
  const float inv0 = 1.f / s0, inv1 = 1.f / s1;

  const size_t rb0 = ((size_t)o0 * qt + q) * 2048 + k0;
  const size_t rb1 = ((size_t)o1 * qt + q) * 2048 + k0;
#pragma unroll
  for (int c = 0; c < 4; ++c) {
    ushort8 p0, p1;
#pragma unroll
    for (int e = 0; e < 8; ++e) {
      p0[e] = f2bf(a0[c * 8 + e] * inv0);
      p1[e] = f2bf(a1[c * 8 + e] * inv1);
    }
    *(ushort8*)&SC[rb0 + c * 8] = p0;
    *(ushort8*)&SC[rb1 + c * 8] = p1;
  }
}

// Diagnostic: fill f32 output with 2000.0 so a ws-too-small failure is
// distinguishable in the absmax report.
__global__ void fill_diag(float* out, int n) {
  int i = blockIdx.x * 256 + threadIdx.x;
  if (i < n) out[i] = 2000.0f;
}

extern "C" void kernel_launch(void* const* d_in, const int* in_sizes, int n_in,
                              void* d_out, int out_size, void* d_ws, size_t ws_size,
                              hipStream_t stream) {
  const float* query = (const float*)d_in[0];
  const float* Wq = (const float*)d_in[1];
  const float* bq = (const float*)d_in[2];
  const float* Wk = (const float*)d_in[3];
  const float* bk = (const float*)d_in[4];
  const float* Wv = (const float*)d_in[5];
  const float* bv = (const float*)d_in[6];
  const float* Wo = (const float*)d_in[7];
  const float* bo = (const float*)d_in[8];
  const float* cw = (const float*)d_in[9];
  // d_in[10] (conv_b) intentionally unused: cancels in softmax.

  const size_t SE = (size_t)4096 * 1024;  // B*S*E elems
  const size_t WE = (size_t)1024 * 1024;  // E*E elems
  const size_t fixedElems = (SE + 4 * WE) + 4 * SE;
  const size_t fixedB = fixedElems * sizeof(u16);  // 48 MiB

  int qt = 0;
  for (int cand = 2048; cand >= 128; cand >>= 1) {
    size_t need = fixedB + (size_t)16 * cand * 2048 * sizeof(u16);
    if (ws_size >= need) { qt = cand; break; }
  }
  if (qt == 0) {
    fill_diag<<<dim3((out_size + 255) / 256), dim3(256), 0, stream>>>(
        (float*)d_out, out_size);
    return;
  }

  u16* ws = (u16*)d_ws;
  u16* Qb = ws;              // bf16 query [b][s][e]
  u16* Wqb = Qb + SE;        // bf16 weights (contiguous after Qb for cvt_all)
  u16* Wkb = Wqb + WE;
  u16* Wvb = Wkb + WE;
  u16* Wob = Wvb + WE;
  u16* Qw = Wob + WE;        // [b][s][e]
  u16* Kw = Qw + SE;         // [b][s][e]
  u16* Vt = Kw + SE;         // [b][e][s] transposed V
  u16* At = Vt + SE;         // attention output [b][s][e] (bf16)
  u16* SC = At + SE;         // scores/weights tile [h][qt][k]

  dim3 blk(256);
  // fused f32 -> bf16 conversion (query + 4 weights), one launch
  cvt_all<<<dim3(4096), blk, 0, stream>>>(query, Wq, Wk, Wv, Wo, Qb);

  // Q/K/V projections (M=4096, N=1024, K=1024), bf16 out
  gemm_nt<128, 128, false, true, false><<<dim3(8, 32, 1), blk, 0, stream>>>(
      Qb, Wqb, bq, Qw, 1024, 1024, 1024, 1024, 1.f, 0, 0, 0);
  gemm_nt<128, 128, false, true, false><<<dim3(8, 32, 1), blk, 0, stream>>>(
      Qb, Wkb, bk, Kw, 1024, 1024, 1024, 1024, 1.f, 0, 0, 0);
  gemm_nt<128, 128, true, true, false><<<dim3(8, 32, 1), blk, 0, stream>>>(
      Qb, Wvb, bv, Vt, 1024, 1024, 1024, 1024, 1.f, 0, 0, 0);

  const long long scTile = (long long)qt * 2048;
  for (int b = 0; b < 2; ++b) {
    for (int q0 = 0; q0 < 2048; q0 += qt) {
      const size_t qkOff = (size_t)b * 2097152 + (size_t)q0 * 1024;
      // scores = Q Kh^T / 8 per head: M=qt, N=2048, K=64, z = head
      gemm_nt<128, 128, false, false, false>
          <<<dim3(16, qt / 128, 16), blk, 0, stream>>>(
              Qw + qkOff, Kw + (size_t)b * 2097152, nullptr, SC,
              64, 1024, 1024, 2048, 0.125f, 64LL, 64LL, scTile);
      // conv across heads + softmax, in place on the tile
      conv_softmax<<<dim3(qt), dim3(512), 0, stream>>>(SC, cw, qt);
      // PV: M=qt (q), N=64 (d), K=2048 (k) per head
      gemm_nt<128, 64, false, false, false>
          <<<dim3(1, qt / 128, 16), blk, 0, stream>>>(
              SC, Vt + (size_t)b * 2097152, nullptr,
              At + qkOff, 2048, 2048, 2048, 1024, 1.f,
              scTile, 131072LL, 64LL);
    }
  }

  // output projection -> f32 d_out
  gemm_nt<128, 128, false, true, true><<<dim3(8, 32, 1), blk, 0, stream>>>(
      At, Wob, bo, d_out, 1024, 1024, 1024, 1024, 1.f, 0, 0, 0);
}

// Round 6
// 499.750 us; speedup vs baseline: 1.1412x; 1.1412x over previous
//
#include <hip/hip_runtime.h>

typedef unsigned short u16;
typedef short short8 __attribute__((ext_vector_type(8)));
typedef unsigned short ushort8 __attribute__((ext_vector_type(8)));
typedef unsigned short bf16x4 __attribute__((ext_vector_type(4)));
typedef float f32x4 __attribute__((ext_vector_type(4)));

#define DEVINL __device__ __forceinline__

DEVINL float bf2f(u16 u) {
  unsigned int x = ((unsigned int)u) << 16;
  return __builtin_bit_cast(float, x);
}
DEVINL u16 f2bf(float f) {
  unsigned int x = __builtin_bit_cast(unsigned int, f);
  x += 0x7FFFu + ((x >> 16) & 1u);  // RNE
  return (u16)(x >> 16);
}

// Problem constants: B=2, S=2048, E=1024, H=16, DH=64
// Inputs float32; big operands converted once to bf16; MFMA internally;
// final output written as float32.

// ---------------------------------------------------------------------------
// Fused f32 -> bf16 conversion of query + 4 weight matrices.
// ---------------------------------------------------------------------------
__global__ __launch_bounds__(256) void cvt_all(
    const float* __restrict__ q, const float* __restrict__ wq,
    const float* __restrict__ wk, const float* __restrict__ wv,
    const float* __restrict__ wo, u16* __restrict__ out) {
  int i = blockIdx.x * 256 + threadIdx.x;  // < 1048576
  const float* src;
  size_t off8;
  if (i < 524288) { src = q;  off8 = i; }
  else if (i < 655360) { src = wq; off8 = i - 524288; }
  else if (i < 786432) { src = wk; off8 = i - 655360; }
  else if (i < 917504) { src = wv; off8 = i - 786432; }
  else { src = wo; off8 = i - 917504; }
  f32x4 a = ((const f32x4*)src)[2 * off8];
  f32x4 b = ((const f32x4*)src)[2 * off8 + 1];
  ushort8 o;
#pragma unroll
  for (int e = 0; e < 4; ++e) o[e] = f2bf(a[e]);
#pragma unroll
  for (int e = 0; e < 4; ++e) o[4 + e] = f2bf(b[e]);
  ((ushort8*)out)[i] = o;
}

// ---------------------------------------------------------------------------
// NT GEMM (bf16 in via MFMA): C[i,j] = scale * sum_k A[i,k]*B[j,k] (+ bias[j])
// ---------------------------------------------------------------------------
template <int BM, int BN, bool TRANSV, bool HASBIAS, bool OUTF32>
__global__ __launch_bounds__(256) void gemm_nt(
    const u16* __restrict__ A, const u16* __restrict__ Bm,
    const float* __restrict__ bias, void* __restrict__ C,
    int K, int lda, int ldb, int ldc, float scale,
    long long sAh, long long sBh, long long sCh) {
  constexpr int LDSS = 40;  // padded LDS row stride (u16)
  constexpr int WM = BM / 2, WN = BN / 2, FM = WM / 16, FN = WN / 16;
  constexpr int AIN = BM / 64;
  constexpr int BIN = BN / 64;

  __shared__ alignas(16) u16 As[BM * LDSS];
  __shared__ alignas(16) u16 Bs[BN * LDSS];

  const int tid = threadIdx.x;
  const int lane = tid & 63;
  const int wv = tid >> 6;
  const int wy = wv >> 1, wx = wv & 1;
  const int quad = lane >> 4, mrow = lane & 15;

  const int z = blockIdx.z;
  const u16* Ap = A + z * sAh;
  const u16* Bp = Bm + z * sBh;
  u16* Cp = (u16*)C + z * sCh;
  float* Cf = (float*)C + z * sCh;

  const int row0 = blockIdx.y * BM;
  const int col0 = blockIdx.x * BN;

  f32x4 acc[FM][FN];
#pragma unroll
  for (int i = 0; i < FM; ++i)
#pragma unroll
    for (int j = 0; j < FN; ++j) acc[i][j] = f32x4{0.f, 0.f, 0.f, 0.f};

  for (int k0 = 0; k0 < K; k0 += 32) {
    ushort8 ta[AIN], tb[BIN];
#pragma unroll
    for (int r = 0; r < AIN; ++r) {
      int idx = r * 256 + tid;
      int row = idx >> 2, ch = idx & 3;
      ta[r] = *(const ushort8*)(Ap + (size_t)(row0 + row) * lda + k0 + ch * 8);
    }
#pragma unroll
    for (int r = 0; r < BIN; ++r) {
      int idx = r * 256 + tid;
      int row = idx >> 2, ch = idx & 3;
      tb[r] = *(const ushort8*)(Bp + (size_t)(col0 + row) * ldb + k0 + ch * 8);
    }
    __syncthreads();  // previous iteration's LDS reads done
#pragma unroll
    for (int r = 0; r < AIN; ++r) {
      int idx = r * 256 + tid;
      int row = idx >> 2, ch = idx & 3;
      *(ushort8*)&As[row * LDSS + ch * 8] = ta[r];
    }
#pragma unroll
    for (int r = 0; r < BIN; ++r) {
      int idx = r * 256 + tid;
      int row = idx >> 2, ch = idx & 3;
      *(ushort8*)&Bs[row * LDSS + ch * 8] = tb[r];
    }
    __syncthreads();

    short8 af[FM], bfr[FN];
#pragma unroll
    for (int mi = 0; mi < FM; ++mi)
      af[mi] = *(const short8*)&As[(wy * WM + mi * 16 + mrow) * LDSS + quad * 8];
#pragma unroll
    for (int ni = 0; ni < FN; ++ni)
      bfr[ni] = *(const short8*)&Bs[(wx * WN + ni * 16 + mrow) * LDSS + quad * 8];
#pragma unroll
    for (int mi = 0; mi < FM; ++mi)
#pragma unroll
      for (int ni = 0; ni < FN; ++ni)
        acc[mi][ni] = __builtin_amdgcn_mfma_f32_16x16x32_bf16(
            af[mi], bfr[ni], acc[mi][ni], 0, 0, 0);
  }

  // Epilogue. C/D layout: col = lane&15, row = quad*4 + r  [m89/m91 verified]
#pragma unroll
  for (int mi = 0; mi < FM; ++mi) {
    const int rowb = row0 + wy * WM + mi * 16 + quad * 4;
#pragma unroll
    for (int ni = 0; ni < FN; ++ni) {
      const int col = col0 + wx * WN + ni * 16 + mrow;
      float bv = 0.f;
      if (HASBIAS) bv = bias[col];
      f32x4 v = acc[mi][ni];
      if (OUTF32) {
#pragma unroll
        for (int r = 0; r < 4; ++r)
          Cf[(size_t)(rowb + r) * ldc + col] = v[r] * scale + bv;
      } else if (!TRANSV) {
#pragma unroll
        for (int r = 0; r < 4; ++r)
          Cp[(size_t)(rowb + r) * ldc + col] = f2bf(v[r] * scale + bv);
      } else {
        // Ct[b][col][s], per-batch stride E*S = 2097152
        const int bb = rowb >> 11;
        const int ss = rowb & 2047;
        bf16x4 pk;
#pragma unroll
        for (int r = 0; r < 4; ++r) pk[r] = f2bf(v[r] * scale + bv);
        *(bf16x4*)(Cp + (size_t)bb * 2097152 + (size_t)col * 2048 + ss) = pk;
      }
    }
  }
}

// ---------------------------------------------------------------------------
// MFMA cross-head conv1d (KS=3, zero pad) + softmax over key axis, in place.
// out[h][k] = sum_{i,d} W[h][i][d] * S[i][k+d-1]  -> as 16x16x32 MFMA:
//   MFMA1: kdim = d*16+i for d in {0,1};  MFMA2: kdim<16 -> d=2, rest zero A.
// LDS rawT[k][h]: row stride 24 u16 (48B = 12 dwords -> conflict-free b128,
// since n*12 mod 32 is a perfect 8-phase permutation). k split in 2 segments
// of 1024 (+2 halo rows) -> 49.3 KB LDS. One block per q: 512 thr = 8 waves;
// wave w owns k-tiles [w*128, w*128+128) per segment (8 tiles of 16).
// Softmax state in registers (C-frag: head = quad*4+r, k = tile*16 + n).
// conv_b skipped: constant along softmax (k) axis -> cancels exactly.
// ---------------------------------------------------------------------------
__global__ __launch_bounds__(512, 2) void conv_softmax(
    u16* __restrict__ SC, const float* __restrict__ cw, int qt) {
  __shared__ alignas(16) u16 rawT[1026 * 24];  // 49.3 KB
  __shared__ float redA[8][16];
  __shared__ float redB[8][16];

  const int tid = threadIdx.x;
  const int lane = tid & 63;
  const int wv = tid >> 6;
  const int q = blockIdx.x;
  const int n = lane & 15;     // MFMA N-index = k-position within tile
  const int quad = lane >> 4;

  // A-frags (conv weights), identical for every tile. A lane's M-row = n.
  short8 a1, a2;
  {
    const int h = n;
#pragma unroll
    for (int j = 0; j < 8; ++j) {
      const int kd = quad * 8 + j;
      const int i = kd & 15, d = kd >> 4;
      a1[j] = (short)f2bf(cw[h * 48 + i * 3 + d]);
      a2[j] = (quad < 2) ? (short)f2bf(cw[h * 48 + kd * 3 + 2]) : (short)0;
    }
  }

  f32x4 acc[16];
#pragma unroll
  for (int ai = 0; ai < 16; ++ai) acc[ai] = f32x4{0.f, 0.f, 0.f, 0.f};

  for (int s = 0; s < 2; ++s) {
    if (s) __syncthreads();  // all reads of previous segment done
    const int segk = s * 1024;
    {  // transpose-load segment into rawT[k-local+1][h]
      const int h = tid & 15, kc = tid >> 4;  // kc in [0,32)
#pragma unroll
      for (int j = 0; j < 4; ++j) {
        const int kb = kc * 32 + j * 8;
        ushort8 v = *(const ushort8*)&SC[((size_t)h * qt + q) * 2048 + segk + kb];
#pragma unroll
        for (int e0 = 0; e0 < 8; ++e0) {
          const int e = (e0 + h) & 7;  // rotation to spread write banks
          rawT[(kb + e + 1) * 24 + h] = v[e];
        }
      }
      if (tid < 32) {  // halo rows: k = segk-1 (row 0) and segk+1024 (row 1025)
        const int h2 = tid & 15;
        const int top = tid >> 4;
        const int k = segk + (top ? 1024 : -1);
        u16 val = 0;
        if ((unsigned)k < 2048u) val = SC[((size_t)h2 * qt + q) * 2048 + k];
        rawT[(top ? 1025 : 0) * 24 + h2] = val;
      }
    }
    __syncthreads();

#pragma unroll
    for (int tt = 0; tt < 8; ++tt) {
      const int k0l = (wv * 8 + tt) * 16;  // local k of tile start
      // local row = (k - segk) + 1 = k0l + n + d  (global k = segk+k0l+n+d-1)
      const short8 b1 = *(const short8*)&rawT[(k0l + n + (quad >> 1)) * 24 + (quad & 1) * 8];
      const short8 b2 = *(const short8*)&rawT[(k0l + n + 2) * 24 + (quad & 1) * 8];
      const int ai = s * 8 + tt;
      acc[ai] = __builtin_amdgcn_mfma_f32_16x16x32_bf16(a1, b1, acc[ai], 0, 0, 0);
      acc[ai] = __builtin_amdgcn_mfma_f32_16x16x32_bf16(a2, b2, acc[ai], 0, 0, 0);
    }
  }

  // ---- softmax over k per head (head = quad*4 + r) ----
  float fm[4];
#pragma unroll
  for (int r = 0; r < 4; ++r) fm[r] = -3e38f;
#pragma unroll
  for (int ai = 0; ai < 16; ++ai)
#pragma unroll
    for (int r = 0; r < 4; ++r) fm[r] = fmaxf(fm[r], acc[ai][r]);
#pragma unroll
  for (int off = 1; off < 16; off <<= 1)
#pragma unroll
    for (int r = 0; r < 4; ++r) fm[r] = fmaxf(fm[r], __shfl_xor(fm[r], off));
  if (n == 0)
#pragma unroll
    for (int r = 0; r < 4; ++r) redA[wv][quad * 4 + r] = fm[r];
  __syncthreads();
#pragma unroll
  for (int r = 0; r < 4; ++r) {
    float m = redA[0][quad * 4 + r];
#pragma unroll
    for (int w = 1; w < 8; ++w) m = fmaxf(m, redA[w][quad * 4 + r]);
    fm[r] = m;
  }
  float fs[4] = {0.f, 0.f, 0.f, 0.f};
#pragma unroll
  for (int ai = 0; ai < 16; ++ai)
#pragma unroll
    for (int r = 0; r < 4; ++r) {
      acc[ai][r] = __expf(acc[ai][r] - fm[r]);
      fs[r] += acc[ai][r];
    }
#pragma unroll
  for (int off = 1; off < 16; off <<= 1)
#pragma unroll
    for (int r = 0; r < 4; ++r) fs[r] += __shfl_xor(fs[r], off);
  if (n == 0)
#pragma unroll
    for (int r = 0; r < 4; ++r) redB[wv][quad * 4 + r] = fs[r];
  __syncthreads();
#pragma unroll
  for (int r = 0; r < 4; ++r) {
    float sum = 0.f;
#pragma unroll
    for (int w = 0; w < 8; ++w) sum += redB[w][quad * 4 + r];
    fs[r] = 1.f / sum;
  }

  // ---- normalize + write back (bf16, in place) ----
#pragma unroll
  for (int ai = 0; ai < 16; ++ai) {
    const int k0 = (ai >> 3) * 1024 + ((ai & 7) + wv * 8) * 16;
#pragma unroll
    for (int r = 0; r < 4; ++r) {
      const int h = quad * 4 + r;
      SC[((size_t)h * qt + q) * 2048 + k0 + n] = f2bf(acc[ai][r] * fs[r]);
    }
  }
}

// Diagnostic: fill f32 output with 2000.0 (ws-too-small marker).
__global__ void fill_diag(float* out, int n) {
  int i = blockIdx.x * 256 + threadIdx.x;
  if (i < n) out[i] = 2000.0f;
}

extern "C" void kernel_launch(void* const* d_in, const int* in_sizes, int n_in,
                              void* d_out, int out_size, void* d_ws, size_t ws_size,
                              hipStream_t stream) {
  const float* query = (const float*)d_in[0];
  const float* Wq = (const float*)d_in[1];
  const float* bq = (const float*)d_in[2];
  const float* Wk = (const float*)d_in[3];
  const float* bk = (const float*)d_in[4];
  const float* Wv = (const float*)d_in[5];
  const float* bv = (const float*)d_in[6];
  const float* Wo = (const float*)d_in[7];
  const float* bo = (const float*)d_in[8];
  const float* cw = (const float*)d_in[9];
  // d_in[10] (conv_b) intentionally unused: cancels in softmax.

  const size_t SE = (size_t)4096 * 1024;  // B*S*E elems
  const size_t WE = (size_t)1024 * 1024;  // E*E elems
  const size_t fixedElems = (SE + 4 * WE) + 4 * SE;
  const size_t fixedB = fixedElems * sizeof(u16);  // 48 MiB

  int qt = 0;
  for (int cand = 2048; cand >= 128; cand >>= 1) {
    size_t need = fixedB + (size_t)16 * cand * 2048 * sizeof(u16);
    if (ws_size >= need) { qt = cand; break; }
  }
  if (qt == 0) {
    fill_diag<<<dim3((out_size + 255) / 256), dim3(256), 0, stream>>>(
        (float*)d_out, out_size);
    return;
  }

  u16* ws = (u16*)d_ws;
  u16* Qb = ws;              // bf16 query [b][s][e]
  u16* Wqb = Qb + SE;        // bf16 weights (contiguous after Qb for cvt_all)
  u16* Wkb = Wqb + WE;
  u16* Wvb = Wkb + WE;
  u16* Wob = Wvb + WE;
  u16* Qw = Wob + WE;        // [b][s][e]
  u16* Kw = Qw + SE;         // [b][s][e]
  u16* Vt = Kw + SE;         // [b][e][s] transposed V
  u16* At = Vt + SE;         // attention output [b][s][e] (bf16)
  u16* SC = At + SE;         // scores/weights tile [h][qt][k]

  dim3 blk(256);
  cvt_all<<<dim3(4096), blk, 0, stream>>>(query, Wq, Wk, Wv, Wo, Qb);

  // Q/K/V projections (M=4096, N=1024, K=1024), bf16 out
  gemm_nt<128, 128, false, true, false><<<dim3(8, 32, 1), blk, 0, stream>>>(
      Qb, Wqb, bq, Qw, 1024, 1024, 1024, 1024, 1.f, 0, 0, 0);
  gemm_nt<128, 128, false, true, false><<<dim3(8, 32, 1), blk, 0, stream>>>(
      Qb, Wkb, bk, Kw, 1024, 1024, 1024, 1024, 1.f, 0, 0, 0);
  gemm_nt<128, 128, true, true, false><<<dim3(8, 32, 1), blk, 0, stream>>>(
      Qb, Wvb, bv, Vt, 1024, 1024, 1024, 1024, 1.f, 0, 0, 0);

  const long long scTile = (long long)qt * 2048;
  for (int b = 0; b < 2; ++b) {
    for (int q0 = 0; q0 < 2048; q0 += qt) {
      const size_t qkOff = (size_t)b * 2097152 + (size_t)q0 * 1024;
      // scores = Q Kh^T / 8 per head: M=qt, N=2048, K=64, z = head
      gemm_nt<128, 128, false, false, false>
          <<<dim3(16, qt / 128, 16), blk, 0, stream>>>(
              Qw + qkOff, Kw + (size_t)b * 2097152, nullptr, SC,
              64, 1024, 1024, 2048, 0.125f, 64LL, 64LL, scTile);
      // MFMA conv across heads + softmax, in place on the tile
      conv_softmax<<<dim3(qt), dim3(512), 0, stream>>>(SC, cw, qt);
      // PV: M=qt (q), N=64 (d), K=2048 (k) per head
      gemm_nt<128, 64, false, false, false>
          <<<dim3(1, qt / 128, 16), blk, 0, stream>>>(
              SC, Vt + (size_t)b * 2097152, nullptr,
              At + qkOff, 2048, 2048, 2048, 1024, 1.f,
              scTile, 131072LL, 64LL);
    }
  }

  // output projection -> f32 d_out
  gemm_nt<128, 128, false, true, true><<<dim3(8, 32, 1), blk, 0, stream>>>(
      At, Wob, bo, d_out, 1024, 1024, 1024, 1024, 1.f, 0, 0, 0);
}